// Round 8
// baseline (459.752 us; speedup 1.0000x reference)
//
#include <hip/hip_runtime.h>
#include <math.h>

#define NLEV 16
#define RES  256
#define NBIN 65536   // 256x256 Morton bins

typedef _Float16 f16;
typedef f16 f16x8 __attribute__((ext_vector_type(8)));
typedef float f32x4 __attribute__((ext_vector_type(4)));

struct LevelMeta {
    float scale[NLEV];
    int   r1[NLEV];    // grid row stride = r+1
    int   off[NLEV];   // element offset into embeddings table
};

__device__ inline f32x4 gload4(const float* p) {
    f32x4 r;
    asm volatile("global_load_dwordx4 %0, %1, off"
                 : "=v"(r) : "v"(p) : "memory");
    return r;
}

__device__ inline unsigned spread2d(unsigned v) {
    v = (v | (v << 4)) & 0x0F0Fu;
    v = (v | (v << 2)) & 0x3333u;
    v = (v | (v << 1)) & 0x5555u;
    return v;
}

__device__ inline unsigned bin_of(float x0, float x1) {
    int bx = (int)(x0 * (float)RES); bx = bx < 0 ? 0 : (bx > RES - 1 ? RES - 1 : bx);
    int by = (int)(x1 * (float)RES); by = by < 0 ? 0 : (by > RES - 1 ? RES - 1 : by);
    return spread2d((unsigned)bx) | (spread2d((unsigned)by) << 1);  // [0, NBIN)
}

// ---- zero the histogram ----
__global__ __launch_bounds__(256)
void zero_kernel(unsigned* __restrict__ hist) {
    ((uint4*)hist)[blockIdx.x * 256 + threadIdx.x] = uint4{0, 0, 0, 0};
}

// ---- hist + bin tag + within-bin rank (single atomic pass) ----
__global__ __launch_bounds__(256)
void hist_kernel(const float* __restrict__ x, const float* __restrict__ cmax,
                 unsigned* __restrict__ hist, unsigned short* __restrict__ bin16,
                 unsigned* __restrict__ seq) {
    int p = blockIdx.x * 256 + threadIdx.x;
    float2 xy = ((const float2*)x)[p];
    unsigned b = bin_of(xy.x / cmax[1], xy.y / cmax[0]);
    unsigned s = atomicAdd(&hist[b], 1u);
    bin16[p] = (unsigned short)b;
    seq[p] = s;
}

// ---- scan phase A ----
__global__ __launch_bounds__(256)
void scanA_kernel(const unsigned* __restrict__ hist, unsigned* __restrict__ sums) {
    __shared__ unsigned ws[4];
    int t = threadIdx.x;
    unsigned s = hist[blockIdx.x * 256 + t];
#pragma unroll
    for (int o = 1; o < 64; o <<= 1) s += (unsigned)__shfl_xor((int)s, o);
    if ((t & 63) == 0) ws[t >> 6] = s;
    __syncthreads();
    if (t == 0) sums[blockIdx.x] = ws[0] + ws[1] + ws[2] + ws[3];
}

// ---- scan phase B ----
__global__ __launch_bounds__(256)
void scanB_kernel(unsigned* __restrict__ sums) {
    __shared__ unsigned ws[4];
    int t = threadIdx.x, lane = t & 63, w = t >> 6;
    unsigned v = sums[t];
    unsigned xs = v;
#pragma unroll
    for (int o = 1; o < 64; o <<= 1) {
        unsigned y = (unsigned)__shfl_up((int)xs, o);
        if (lane >= o) xs += y;
    }
    if (lane == 63) ws[w] = xs;
    __syncthreads();
    unsigned wo = 0;
    for (int k = 0; k < w; ++k) wo += ws[k];
    sums[t] = wo + xs - v;  // exclusive
}

// ---- scan phase C ----
__global__ __launch_bounds__(256)
void scanC_kernel(const unsigned* __restrict__ hist, const unsigned* __restrict__ sums,
                  unsigned* __restrict__ base) {
    __shared__ unsigned ws[4];
    int t = threadIdx.x, lane = t & 63, w = t >> 6;
    int gb = blockIdx.x * 256 + t;
    unsigned v = hist[gb];
    unsigned xs = v;
#pragma unroll
    for (int o = 1; o < 64; o <<= 1) {
        unsigned y = (unsigned)__shfl_up((int)xs, o);
        if (lane >= o) xs += y;
    }
    if (lane == 63) ws[w] = xs;
    __syncthreads();
    unsigned wo = 0;
    for (int k = 0; k < w; ++k) wo += ws[k];
    base[gb] = sums[blockIdx.x] + wo + xs - v;
}

// ---- scatter: atomic-free; writes pidx AND sorted normalized coords ----
__global__ __launch_bounds__(256)
void scatter_kernel(const float* __restrict__ x, const float* __restrict__ cmax,
                    const unsigned short* __restrict__ bin16,
                    const unsigned* __restrict__ seq,
                    const unsigned* __restrict__ base,
                    unsigned* __restrict__ pidx, float2* __restrict__ px) {
    int p = blockIdx.x * 256 + threadIdx.x;
    unsigned b = bin16[p];
    unsigned rank = base[b] + seq[p];
    pidx[rank] = (unsigned)p;
    float2 xy = ((const float2*)x)[p];
    float2 v; v.x = xy.x / cmax[1]; v.y = xy.y / cmax[0];
    px[rank] = v;
}

// ---- encode: sorted order, forced-batch gathers, writes out_lc0 ----
// No LDS. asm-volatile loads are mutually ordered -> 16 truly in flight.
__global__ __launch_bounds__(256, 4)
void encode_kernel(const float* __restrict__ x,
                   const float* __restrict__ cmax,
                   const unsigned* __restrict__ pidx,   // may be null
                   const float2* __restrict__ px,       // may be null
                   const float* __restrict__ emb,
                   float* __restrict__ out,
                   int npts, int nblk,
                   LevelMeta meta)
{
    int bid = blockIdx.x;
    int cpx = nblk >> 3;
    int swz = (bid & 7) * cpx + (bid >> 3);
    const int g = swz * 256 + threadIdx.x;

    int p;
    float x0, x1;
    if (pidx) {
        p = (int)pidx[g];
        float2 xy = px[g];
        x0 = xy.x; x1 = xy.y;
    } else {
        p = g;
        float2 xy = ((const float2*)x)[p];
        x0 = xy.x / cmax[1];
        x1 = xy.y / cmax[0];
    }

    float* outlc = out + (size_t)npts * 3 + (size_t)p * 32;

#pragma unroll
    for (int hh = 0; hh < 2; ++hh) {
        f32x4 lo[8], hi[8];
#pragma unroll
        for (int i = 0; i < 8; ++i) {
            const int l = hh * 8 + i;
            float p0 = x0 * meta.scale[l] + 0.5f;
            float p1 = x1 * meta.scale[l] + 0.5f;
            int i0 = (int)floorf(p0);
            int i1 = (int)floorf(p1);
            const float* ebf = emb + 2 * (meta.off[l] + i1 * meta.r1[l] + i0);
            lo[i] = gload4(ebf);                      // e00 e10
            hi[i] = gload4(ebf + 2 * meta.r1[l]);     // e01 e11
        }
        asm volatile("s_waitcnt vmcnt(0)" ::: "memory");
        __builtin_amdgcn_sched_barrier(0);

        float fr[16];
#pragma unroll
        for (int i = 0; i < 8; ++i) {
            const int l = hh * 8 + i;
            float p0 = x0 * meta.scale[l] + 0.5f;
            float p1 = x1 * meta.scale[l] + 0.5f;
            float g0 = floorf(p0), g1 = floorf(p1);
            float f0 = p0 - g0, f1 = p1 - g1;
            float omf0 = 1.f - f0, omf1 = 1.f - f1;
            float w00 = omf0 * omf1, w01 = omf0 * f1, w10 = f0 * omf1, w11 = f0 * f1;
            float a0 = w00 * lo[i][0]; a0 += w01 * hi[i][0]; a0 += w10 * lo[i][2]; a0 += w11 * hi[i][2];
            float a1 = w00 * lo[i][1]; a1 += w01 * hi[i][1]; a1 += w10 * lo[i][3]; a1 += w11 * hi[i][3];
            fr[2 * i]     = a0;
            fr[2 * i + 1] = a1;
        }
#pragma unroll
        for (int c = 0; c < 4; ++c) {
            float4 v;
            v.x = fr[4 * c]; v.y = fr[4 * c + 1]; v.z = fr[4 * c + 2]; v.w = fr[4 * c + 3];
            ((float4*)outlc)[hh * 4 + c] = v;
        }
    }
}

// ---- MLP: original order, streaming lc0 -> h ----
// LDS: per-wave h transpose buffer only (36864B -> 4 WG/CU).
__global__ __launch_bounds__(256, 4)
void mlp_kernel(const float* __restrict__ lc,   // = out + npts*3
                const float* __restrict__ w0,
                const float* __restrict__ b0,
                const float* __restrict__ w1,
                const float* __restrict__ b1,
                const float* __restrict__ w2,
                const float* __restrict__ b2,
                float* __restrict__ out,
                int npts)
{
    __shared__ f16 wbuf[4][4608];  // per-wave h [64][72]

    const int tid  = threadIdx.x;
    const int lane = tid & 63;
    const int wave = tid >> 6;
    const int g0 = blockIdx.x * 256 + wave * 64;   // wave's first point (original order)

    const int lr = lane & 15;
    const int lg = lane >> 4;
    f16* hbuf = wbuf[wave];

    // layer-0 A fragments straight from memory: feats[pt][lg*8 .. +8]
    f16x8 afr[4];
#pragma unroll
    for (int mt = 0; mt < 4; ++mt) {
        const float* fp = lc + (size_t)(g0 + mt * 16 + lr) * 32 + lg * 8;
        float4 fa = ((const float4*)fp)[0];
        float4 fb = ((const float4*)fp)[1];
        f16x8 v;
        v[0] = (f16)(fmaxf(fa.x, 0.f) * 16384.f);
        v[1] = (f16)(fmaxf(fa.y, 0.f) * 16384.f);
        v[2] = (f16)(fmaxf(fa.z, 0.f) * 16384.f);
        v[3] = (f16)(fmaxf(fa.w, 0.f) * 16384.f);
        v[4] = (f16)(fmaxf(fb.x, 0.f) * 16384.f);
        v[5] = (f16)(fmaxf(fb.y, 0.f) * 16384.f);
        v[6] = (f16)(fmaxf(fb.z, 0.f) * 16384.f);
        v[7] = (f16)(fmaxf(fb.w, 0.f) * 16384.f);
        afr[mt] = v;
    }

    // layer 0
    {
        f16x8 bf[4];
        float bia[4];
#pragma unroll
        for (int nt = 0; nt < 4; ++nt) {
            const float* wr = w0 + (nt * 16 + lr) * 32 + lg * 8;
            float4 wa = ((const float4*)wr)[0];
            float4 wb = ((const float4*)wr)[1];
            f16x8 v;
            v[0] = (f16)wa.x; v[1] = (f16)wa.y; v[2] = (f16)wa.z; v[3] = (f16)wa.w;
            v[4] = (f16)wb.x; v[5] = (f16)wb.y; v[6] = (f16)wb.z; v[7] = (f16)wb.w;
            bf[nt] = v;
            bia[nt] = b0[nt * 16 + lr];
        }
#pragma unroll
        for (int mt = 0; mt < 4; ++mt) {
            __builtin_amdgcn_s_setprio(1);
            f32x4 c[4];
#pragma unroll
            for (int nt = 0; nt < 4; ++nt) {
                f32x4 z = {0.f, 0.f, 0.f, 0.f};
                c[nt] = __builtin_amdgcn_mfma_f32_16x16x32_f16(afr[mt], bf[nt], z, 0, 0, 0);
            }
            __builtin_amdgcn_s_setprio(0);
#pragma unroll
            for (int nt = 0; nt < 4; ++nt)
#pragma unroll
                for (int q = 0; q < 4; ++q) {
                    float h = fmaxf(c[nt][q] * (1.0f / 16384.f) + bia[nt], 0.f);
                    hbuf[(mt * 16 + lg * 4 + q) * 72 + nt * 16 + lr] = (f16)h;
                }
        }
    }

    // layer 1
    {
        f16x8 bf[4][2];
        float bia[4];
#pragma unroll
        for (int nt = 0; nt < 4; ++nt) {
            const float* wr = w1 + (nt * 16 + lr) * 64;
#pragma unroll
            for (int h = 0; h < 2; ++h) {
                float4 wa = ((const float4*)(wr + 32 * h + lg * 8))[0];
                float4 wb = ((const float4*)(wr + 32 * h + lg * 8))[1];
                f16x8 v;
                v[0] = (f16)wa.x; v[1] = (f16)wa.y; v[2] = (f16)wa.z; v[3] = (f16)wa.w;
                v[4] = (f16)wb.x; v[5] = (f16)wb.y; v[6] = (f16)wb.z; v[7] = (f16)wb.w;
                bf[nt][h] = v;
            }
            bia[nt] = b1[nt * 16 + lr];
        }
#pragma unroll
        for (int mt = 0; mt < 4; ++mt) {
            f16x8 a0 = *(const f16x8*)&hbuf[(mt * 16 + lr) * 72 + lg * 8];
            f16x8 a1 = *(const f16x8*)&hbuf[(mt * 16 + lr) * 72 + 32 + lg * 8];
            __builtin_amdgcn_s_setprio(1);
            f32x4 c[4];
#pragma unroll
            for (int nt = 0; nt < 4; ++nt) {
                f32x4 z = {0.f, 0.f, 0.f, 0.f};
                z = __builtin_amdgcn_mfma_f32_16x16x32_f16(a0, bf[nt][0], z, 0, 0, 0);
                c[nt] = __builtin_amdgcn_mfma_f32_16x16x32_f16(a1, bf[nt][1], z, 0, 0, 0);
            }
            __builtin_amdgcn_s_setprio(0);
#pragma unroll
            for (int nt = 0; nt < 4; ++nt)
#pragma unroll
                for (int q = 0; q < 4; ++q) {
                    float h = fmaxf(c[nt][q] + bia[nt], 0.f);
                    hbuf[(mt * 16 + lg * 4 + q) * 72 + nt * 16 + lr] = (f16)h;
                }
        }
    }

    // layer 2 -> h output, original order (streaming)
    {
        f16x8 bf0 = {};
        f16x8 bf1 = {};
        float bia2 = 0.f;
        if (lr < 3) {
            const float* wr = w2 + lr * 64;
#pragma unroll
            for (int h = 0; h < 2; ++h) {
                float4 wa = ((const float4*)(wr + 32 * h + lg * 8))[0];
                float4 wb = ((const float4*)(wr + 32 * h + lg * 8))[1];
                f16x8 v;
                v[0] = (f16)wa.x; v[1] = (f16)wa.y; v[2] = (f16)wa.z; v[3] = (f16)wa.w;
                v[4] = (f16)wb.x; v[5] = (f16)wb.y; v[6] = (f16)wb.z; v[7] = (f16)wb.w;
                if (h) bf1 = v; else bf0 = v;
            }
            bia2 = b2[lr];
        }
#pragma unroll
        for (int mt = 0; mt < 4; ++mt) {
            f16x8 a0 = *(const f16x8*)&hbuf[(mt * 16 + lr) * 72 + lg * 8];
            f16x8 a1 = *(const f16x8*)&hbuf[(mt * 16 + lr) * 72 + 32 + lg * 8];
            __builtin_amdgcn_s_setprio(1);
            f32x4 c = {0.f, 0.f, 0.f, 0.f};
            c = __builtin_amdgcn_mfma_f32_16x16x32_f16(a0, bf0, c, 0, 0, 0);
            c = __builtin_amdgcn_mfma_f32_16x16x32_f16(a1, bf1, c, 0, 0, 0);
            __builtin_amdgcn_s_setprio(0);
            if (lr < 3) {
#pragma unroll
                for (int q = 0; q < 4; ++q) {
                    int row = mt * 16 + lg * 4 + q;
                    out[(size_t)(g0 + row) * 3 + lr] = c[q] + bia2;
                }
            }
        }
    }
}

extern "C" void kernel_launch(void* const* d_in, const int* in_sizes, int n_in,
                              void* d_out, int out_size, void* d_ws, size_t ws_size,
                              hipStream_t stream) {
    const float* x    = (const float*)d_in[0];
    const float* cmax = (const float*)d_in[1];
    const float* emb  = (const float*)d_in[2];
    const float* w0   = (const float*)d_in[3];
    const float* b0   = (const float*)d_in[4];
    const float* w1   = (const float*)d_in[5];
    const float* b1   = (const float*)d_in[6];
    const float* w2   = (const float*)d_in[7];
    const float* b2   = (const float*)d_in[8];
    const int npts = in_sizes[0] / 2;
    const int nblk = npts / 256;

    LevelMeta meta;
    const double S = log2(2048.0 / 16.0) / 15.0;
    long long off = 0;
    for (int l = 0; l < NLEV; ++l) {
        double s = pow(2.0, l * S) * 16.0 - 1.0;
        int r = (int)ceil(s) + 1;
        long long pc = (long long)(r + 1) * (r + 1);
        if (pc > (1ll << 24)) pc = (1ll << 24);
        pc = ((pc + 7) / 8) * 8;
        meta.scale[l] = (float)s;
        meta.r1[l]    = r + 1;
        meta.off[l]   = (int)off;
        off += pc;
    }

    float* outp = (float*)d_out;
    const float* lc = outp + (size_t)npts * 3;

    // ws: hist[NBIN] u32 | base[NBIN] u32 | sums[256] u32 | pidx u32 | seq u32 | px f2 | bin16 u16
    size_t need = (size_t)NBIN * 8 + 256 * 4 + (size_t)npts * 18;
    if (ws_size >= need && (npts & 255) == 0 && (nblk & 7) == 0) {
        unsigned* hist = (unsigned*)d_ws;
        unsigned* base = hist + NBIN;
        unsigned* sums = base + NBIN;
        unsigned* pidx = sums + 256;
        unsigned* seq  = pidx + npts;
        float2*   px   = (float2*)(seq + npts);
        unsigned short* bin16 = (unsigned short*)(px + npts);

        hipLaunchKernelGGL(zero_kernel, dim3(NBIN / 1024), dim3(256), 0, stream, hist);
        hipLaunchKernelGGL(hist_kernel, dim3(nblk), dim3(256), 0, stream, x, cmax, hist, bin16, seq);
        hipLaunchKernelGGL(scanA_kernel, dim3(NBIN / 256), dim3(256), 0, stream, hist, sums);
        hipLaunchKernelGGL(scanB_kernel, dim3(1), dim3(256), 0, stream, sums);
        hipLaunchKernelGGL(scanC_kernel, dim3(NBIN / 256), dim3(256), 0, stream, hist, sums, base);
        hipLaunchKernelGGL(scatter_kernel, dim3(nblk), dim3(256), 0, stream, x, cmax, bin16, seq, base, pidx, px);
        hipLaunchKernelGGL(encode_kernel, dim3(nblk), dim3(256), 0, stream,
                           x, cmax, pidx, px, emb, outp, npts, nblk, meta);
    } else {
        hipLaunchKernelGGL(encode_kernel, dim3(nblk), dim3(256), 0, stream,
                           x, cmax, (const unsigned*)nullptr, (const float2*)nullptr,
                           emb, outp, npts, nblk, meta);
    }
    hipLaunchKernelGGL(mlp_kernel, dim3(nblk), dim3(256), 0, stream,
                       lc, w0, b0, w1, b1, w2, b2, outp, npts);
}

// Round 10
// 431.342 us; speedup vs baseline: 1.0659x; 1.0659x over previous
//
#include <hip/hip_runtime.h>
#include <math.h>

#define NLEV 16
#define RES  256
#define NBIN 65536   // 256x256 Morton bins

typedef _Float16 f16;
typedef f16 f16x8 __attribute__((ext_vector_type(8)));
typedef float f32x4 __attribute__((ext_vector_type(4)));

struct LevelMeta {
    float scale[NLEV];
    int   r1[NLEV];    // grid row stride = r+1
    int   off[NLEV];   // element offset into embeddings table
};

__device__ inline f32x4 gload4(const float* p) {
    f32x4 r;
    asm volatile("global_load_dwordx4 %0, %1, off"
                 : "=v"(r) : "v"(p) : "memory");
    return r;
}

__device__ inline unsigned spread2d(unsigned v) {
    v = (v | (v << 4)) & 0x0F0Fu;
    v = (v | (v << 2)) & 0x3333u;
    v = (v | (v << 1)) & 0x5555u;
    return v;
}

__device__ inline unsigned bin_of(float x0, float x1) {
    int bx = (int)(x0 * (float)RES); bx = bx < 0 ? 0 : (bx > RES - 1 ? RES - 1 : bx);
    int by = (int)(x1 * (float)RES); by = by < 0 ? 0 : (by > RES - 1 ? RES - 1 : by);
    return spread2d((unsigned)bx) | (spread2d((unsigned)by) << 1);  // [0, NBIN)
}

// ---- zero the histogram ----
__global__ __launch_bounds__(256)
void zero_kernel(unsigned* __restrict__ hist) {
    ((uint4*)hist)[blockIdx.x * 256 + threadIdx.x] = uint4{0, 0, 0, 0};
}

// ---- hist + bin tag + within-bin rank (single atomic pass) ----
__global__ __launch_bounds__(256)
void hist_kernel(const float* __restrict__ x, const float* __restrict__ cmax,
                 unsigned* __restrict__ hist, unsigned short* __restrict__ bin16,
                 unsigned* __restrict__ seq) {
    int p = blockIdx.x * 256 + threadIdx.x;
    float2 xy = ((const float2*)x)[p];
    unsigned b = bin_of(xy.x / cmax[1], xy.y / cmax[0]);
    unsigned s = atomicAdd(&hist[b], 1u);
    bin16[p] = (unsigned short)b;
    seq[p] = s;
}

// ---- scan phase A ----
__global__ __launch_bounds__(256)
void scanA_kernel(const unsigned* __restrict__ hist, unsigned* __restrict__ sums) {
    __shared__ unsigned ws[4];
    int t = threadIdx.x;
    unsigned s = hist[blockIdx.x * 256 + t];
#pragma unroll
    for (int o = 1; o < 64; o <<= 1) s += (unsigned)__shfl_xor((int)s, o);
    if ((t & 63) == 0) ws[t >> 6] = s;
    __syncthreads();
    if (t == 0) sums[blockIdx.x] = ws[0] + ws[1] + ws[2] + ws[3];
}

// ---- scan phase B ----
__global__ __launch_bounds__(256)
void scanB_kernel(unsigned* __restrict__ sums) {
    __shared__ unsigned ws[4];
    int t = threadIdx.x, lane = t & 63, w = t >> 6;
    unsigned v = sums[t];
    unsigned xs = v;
#pragma unroll
    for (int o = 1; o < 64; o <<= 1) {
        unsigned y = (unsigned)__shfl_up((int)xs, o);
        if (lane >= o) xs += y;
    }
    if (lane == 63) ws[w] = xs;
    __syncthreads();
    unsigned wo = 0;
    for (int k = 0; k < w; ++k) wo += ws[k];
    sums[t] = wo + xs - v;  // exclusive
}

// ---- scan phase C ----
__global__ __launch_bounds__(256)
void scanC_kernel(const unsigned* __restrict__ hist, const unsigned* __restrict__ sums,
                  unsigned* __restrict__ base) {
    __shared__ unsigned ws[4];
    int t = threadIdx.x, lane = t & 63, w = t >> 6;
    int gb = blockIdx.x * 256 + t;
    unsigned v = hist[gb];
    unsigned xs = v;
#pragma unroll
    for (int o = 1; o < 64; o <<= 1) {
        unsigned y = (unsigned)__shfl_up((int)xs, o);
        if (lane >= o) xs += y;
    }
    if (lane == 63) ws[w] = xs;
    __syncthreads();
    unsigned wo = 0;
    for (int k = 0; k < w; ++k) wo += ws[k];
    base[gb] = sums[blockIdx.x] + wo + xs - v;
}

// ---- scatter: atomic-free; writes pidx AND sorted normalized coords ----
__global__ __launch_bounds__(256)
void scatter_kernel(const float* __restrict__ x, const float* __restrict__ cmax,
                    const unsigned short* __restrict__ bin16,
                    const unsigned* __restrict__ seq,
                    const unsigned* __restrict__ base,
                    unsigned* __restrict__ pidx, float2* __restrict__ px) {
    int p = blockIdx.x * 256 + threadIdx.x;
    unsigned b = bin16[p];
    unsigned rank = base[b] + seq[p];
    pidx[rank] = (unsigned)p;
    float2 xy = ((const float2*)x)[p];
    float2 v; v.x = xy.x / cmax[1]; v.y = xy.y / cmax[0];
    px[rank] = v;
}

// ---- fused hashgrid + MLP ----
// LDS: wbuf 36864B -> 4 WG/CU. Gather: per-half 16-load asm batch (round-8-proven),
// vmcnt(0) drain + sched_barrier(0) per rule #18.
__global__ __launch_bounds__(256, 4)
void hashmlp_kernel(const float* __restrict__ x,
                    const float* __restrict__ cmax,
                    const unsigned* __restrict__ pidx,   // may be null (fallback)
                    const float2* __restrict__ px,       // may be null
                    const float* __restrict__ emb,
                    const float* __restrict__ w0,
                    const float* __restrict__ b0,
                    const float* __restrict__ w1,
                    const float* __restrict__ b1,
                    const float* __restrict__ w2,
                    const float* __restrict__ b2,
                    float* __restrict__ out,
                    int npts, int nblk,
                    LevelMeta meta)
{
    __shared__ f16 wbuf[4][4608];  // per-wave: feats [64][40] then h [64][72]

    const int tid  = threadIdx.x;
    const int lane = tid & 63;
    const int wave = tid >> 6;

    // XCD-chunked swizzle: contiguous sorted (spatial) range per XCD
    int bid = blockIdx.x;
    int cpx = nblk >> 3;
    int swz = (bid & 7) * cpx + (bid >> 3);
    const int g = swz * 256 + tid;
    const int gblk = swz * 256 + wave * 64;

    int p;
    float x0, x1;
    if (pidx) {
        p = (int)pidx[g];
        float2 xy = px[g];          // streaming read of sorted coords
        x0 = xy.x; x1 = xy.y;
    } else {
        p = g;
        float2 xy = ((const float2*)x)[p];
        x0 = xy.x / cmax[1];
        x1 = xy.y / cmax[0];
    }

    float* outlc = out + (size_t)npts * 3 + (size_t)p * 32;
    f16* fbuf = wbuf[wave];
    float fr[32];

    // gather: two halves, each = 16 asm loads in flight -> drain -> consume
#pragma unroll
    for (int hh = 0; hh < 2; ++hh) {
        f32x4 lo[8], hi[8];
#pragma unroll
        for (int i = 0; i < 8; ++i) {
            const int l = hh * 8 + i;
            float p0 = x0 * meta.scale[l] + 0.5f;
            float p1 = x1 * meta.scale[l] + 0.5f;
            int i0 = (int)floorf(p0);
            int i1 = (int)floorf(p1);
            const float* ebf = emb + 2 * (meta.off[l] + i1 * meta.r1[l] + i0);
            lo[i] = gload4(ebf);                      // e00 e10
            hi[i] = gload4(ebf + 2 * meta.r1[l]);     // e01 e11
        }
        asm volatile("s_waitcnt vmcnt(0)" ::: "memory");
        __builtin_amdgcn_sched_barrier(0);

#pragma unroll
        for (int i = 0; i < 8; ++i) {
            const int l = hh * 8 + i;
            float p0 = x0 * meta.scale[l] + 0.5f;
            float p1 = x1 * meta.scale[l] + 0.5f;
            float g0 = floorf(p0), g1 = floorf(p1);
            float f0 = p0 - g0, f1 = p1 - g1;
            float omf0 = 1.f - f0, omf1 = 1.f - f1;
            float w00 = omf0 * omf1, w01 = omf0 * f1, w10 = f0 * omf1, w11 = f0 * f1;
            float a0 = w00 * lo[i][0]; a0 += w01 * hi[i][0]; a0 += w10 * lo[i][2]; a0 += w11 * hi[i][2];
            float a1 = w00 * lo[i][1]; a1 += w01 * hi[i][1]; a1 += w10 * lo[i][3]; a1 += w11 * hi[i][3];
            fr[2 * l]     = a0;
            fr[2 * l + 1] = a1;
        }

        // out_lc0 half (fp32, exact) at original position — via L2
#pragma unroll
        for (int c = 0; c < 4; ++c) {
            float4 v;
            v.x = fr[hh * 16 + 4 * c];     v.y = fr[hh * 16 + 4 * c + 1];
            v.z = fr[hh * 16 + 4 * c + 2]; v.w = fr[hh * 16 + 4 * c + 3];
            ((float4*)outlc)[hh * 4 + c] = v;
        }

        // stage relu(feats)*2^14 as f16 into per-wave LDS [64][40], half hh
#pragma unroll
        for (int c = 0; c < 2; ++c) {
            f16x8 v;
#pragma unroll
            for (int j = 0; j < 8; ++j)
                v[j] = (f16)(fmaxf(fr[hh * 16 + 8 * c + j], 0.f) * 16384.f);
            *(f16x8*)&fbuf[lane * 40 + hh * 16 + c * 8] = v;
        }
    }

    const int lr = lane & 15;
    const int lg = lane >> 4;
    f16* hbuf = wbuf[wave];

    // layer 0: weights from global (L2-hot) into register fragments
    {
        f16x8 bf[4];
        float bia[4];
#pragma unroll
        for (int nt = 0; nt < 4; ++nt) {
            const float* wr = w0 + (nt * 16 + lr) * 32 + lg * 8;
            float4 wa = ((const float4*)wr)[0];
            float4 wb = ((const float4*)wr)[1];
            f16x8 v;
            v[0] = (f16)wa.x; v[1] = (f16)wa.y; v[2] = (f16)wa.z; v[3] = (f16)wa.w;
            v[4] = (f16)wb.x; v[5] = (f16)wb.y; v[6] = (f16)wb.z; v[7] = (f16)wb.w;
            bf[nt] = v;
            bia[nt] = b0[nt * 16 + lr];
        }
#pragma unroll
        for (int mt = 3; mt >= 0; --mt) {
            f16x8 a = *(const f16x8*)&fbuf[(mt * 16 + lr) * 40 + lg * 8];
            __builtin_amdgcn_s_setprio(1);
            f32x4 c[4];
#pragma unroll
            for (int nt = 0; nt < 4; ++nt) {
                f32x4 z = {0.f, 0.f, 0.f, 0.f};
                c[nt] = __builtin_amdgcn_mfma_f32_16x16x32_f16(a, bf[nt], z, 0, 0, 0);
            }
            __builtin_amdgcn_s_setprio(0);
#pragma unroll
            for (int nt = 0; nt < 4; ++nt)
#pragma unroll
                for (int q = 0; q < 4; ++q) {
                    float h = fmaxf(c[nt][q] * (1.0f / 16384.f) + bia[nt], 0.f);
                    hbuf[(mt * 16 + lg * 4 + q) * 72 + nt * 16 + lr] = (f16)h;
                }
        }
    }

    // layer 1
    {
        f16x8 bf[4][2];
        float bia[4];
#pragma unroll
        for (int nt = 0; nt < 4; ++nt) {
            const float* wr = w1 + (nt * 16 + lr) * 64;
#pragma unroll
            for (int h = 0; h < 2; ++h) {
                float4 wa = ((const float4*)(wr + 32 * h + lg * 8))[0];
                float4 wb = ((const float4*)(wr + 32 * h + lg * 8))[1];
                f16x8 v;
                v[0] = (f16)wa.x; v[1] = (f16)wa.y; v[2] = (f16)wa.z; v[3] = (f16)wa.w;
                v[4] = (f16)wb.x; v[5] = (f16)wb.y; v[6] = (f16)wb.z; v[7] = (f16)wb.w;
                bf[nt][h] = v;
            }
            bia[nt] = b1[nt * 16 + lr];
        }
#pragma unroll
        for (int mt = 0; mt < 4; ++mt) {
            f16x8 a0 = *(const f16x8*)&hbuf[(mt * 16 + lr) * 72 + lg * 8];
            f16x8 a1 = *(const f16x8*)&hbuf[(mt * 16 + lr) * 72 + 32 + lg * 8];
            __builtin_amdgcn_s_setprio(1);
            f32x4 c[4];
#pragma unroll
            for (int nt = 0; nt < 4; ++nt) {
                f32x4 z = {0.f, 0.f, 0.f, 0.f};
                z = __builtin_amdgcn_mfma_f32_16x16x32_f16(a0, bf[nt][0], z, 0, 0, 0);
                c[nt] = __builtin_amdgcn_mfma_f32_16x16x32_f16(a1, bf[nt][1], z, 0, 0, 0);
            }
            __builtin_amdgcn_s_setprio(0);
#pragma unroll
            for (int nt = 0; nt < 4; ++nt)
#pragma unroll
                for (int q = 0; q < 4; ++q) {
                    float h = fmaxf(c[nt][q] + bia[nt], 0.f);
                    hbuf[(mt * 16 + lg * 4 + q) * 72 + nt * 16 + lr] = (f16)h;
                }
        }
    }

    // layer 2 -> h output at original positions (via L2)
    {
        f16x8 bf0 = {};
        f16x8 bf1 = {};
        float bia2 = 0.f;
        if (lr < 3) {
            const float* wr = w2 + lr * 64;
#pragma unroll
            for (int h = 0; h < 2; ++h) {
                float4 wa = ((const float4*)(wr + 32 * h + lg * 8))[0];
                float4 wb = ((const float4*)(wr + 32 * h + lg * 8))[1];
                f16x8 v;
                v[0] = (f16)wa.x; v[1] = (f16)wa.y; v[2] = (f16)wa.z; v[3] = (f16)wa.w;
                v[4] = (f16)wb.x; v[5] = (f16)wb.y; v[6] = (f16)wb.z; v[7] = (f16)wb.w;
                if (h) bf1 = v; else bf0 = v;
            }
            bia2 = b2[lr];
        }
#pragma unroll
        for (int mt = 0; mt < 4; ++mt) {
            f16x8 a0 = *(const f16x8*)&hbuf[(mt * 16 + lr) * 72 + lg * 8];
            f16x8 a1 = *(const f16x8*)&hbuf[(mt * 16 + lr) * 72 + 32 + lg * 8];
            __builtin_amdgcn_s_setprio(1);
            f32x4 c = {0.f, 0.f, 0.f, 0.f};
            c = __builtin_amdgcn_mfma_f32_16x16x32_f16(a0, bf0, c, 0, 0, 0);
            c = __builtin_amdgcn_mfma_f32_16x16x32_f16(a1, bf1, c, 0, 0, 0);
            __builtin_amdgcn_s_setprio(0);
            if (lr < 3) {
#pragma unroll
                for (int q = 0; q < 4; ++q) {
                    int row = mt * 16 + lg * 4 + q;
                    int po = pidx ? (int)pidx[gblk + row] : (gblk + row);
                    out[(size_t)po * 3 + lr] = c[q] + bia2;
                }
            }
        }
    }
}

extern "C" void kernel_launch(void* const* d_in, const int* in_sizes, int n_in,
                              void* d_out, int out_size, void* d_ws, size_t ws_size,
                              hipStream_t stream) {
    const float* x    = (const float*)d_in[0];
    const float* cmax = (const float*)d_in[1];
    const float* emb  = (const float*)d_in[2];
    const float* w0   = (const float*)d_in[3];
    const float* b0   = (const float*)d_in[4];
    const float* w1   = (const float*)d_in[5];
    const float* b1   = (const float*)d_in[6];
    const float* w2   = (const float*)d_in[7];
    const float* b2   = (const float*)d_in[8];
    const int npts = in_sizes[0] / 2;
    const int nblk = npts / 256;

    LevelMeta meta;
    const double S = log2(2048.0 / 16.0) / 15.0;
    long long off = 0;
    for (int l = 0; l < NLEV; ++l) {
        double s = pow(2.0, l * S) * 16.0 - 1.0;
        int r = (int)ceil(s) + 1;
        long long pc = (long long)(r + 1) * (r + 1);
        if (pc > (1ll << 24)) pc = (1ll << 24);
        pc = ((pc + 7) / 8) * 8;
        meta.scale[l] = (float)s;
        meta.r1[l]    = r + 1;
        meta.off[l]   = (int)off;
        off += pc;
    }

    // ws: hist[NBIN] u32 | base[NBIN] u32 | sums[256] u32 | pidx u32 | seq u32 | px f2 | bin16 u16
    size_t need = (size_t)NBIN * 8 + 256 * 4 + (size_t)npts * 18;
    if (ws_size >= need && (npts & 255) == 0 && (nblk & 7) == 0) {
        unsigned* hist = (unsigned*)d_ws;
        unsigned* base = hist + NBIN;
        unsigned* sums = base + NBIN;
        unsigned* pidx = sums + 256;
        unsigned* seq  = pidx + npts;
        float2*   px   = (float2*)(seq + npts);
        unsigned short* bin16 = (unsigned short*)(px + npts);

        hipLaunchKernelGGL(zero_kernel, dim3(NBIN / 1024), dim3(256), 0, stream, hist);
        hipLaunchKernelGGL(hist_kernel, dim3(nblk), dim3(256), 0, stream, x, cmax, hist, bin16, seq);
        hipLaunchKernelGGL(scanA_kernel, dim3(NBIN / 256), dim3(256), 0, stream, hist, sums);
        hipLaunchKernelGGL(scanB_kernel, dim3(1), dim3(256), 0, stream, sums);
        hipLaunchKernelGGL(scanC_kernel, dim3(NBIN / 256), dim3(256), 0, stream, hist, sums, base);
        hipLaunchKernelGGL(scatter_kernel, dim3(nblk), dim3(256), 0, stream, x, cmax, bin16, seq, base, pidx, px);
        hipLaunchKernelGGL(hashmlp_kernel, dim3(nblk), dim3(256), 0, stream,
                           x, cmax, pidx, px, emb, w0, b0, w1, b1, w2, b2,
                           (float*)d_out, npts, nblk, meta);
    } else {
        hipLaunchKernelGGL(hashmlp_kernel, dim3(nblk), dim3(256), 0, stream,
                           x, cmax, (const unsigned*)nullptr, (const float2*)nullptr,
                           emb, w0, b0, w1, b1, w2, b2,
                           (float*)d_out, npts, nblk, meta);
    }
}

// Round 11
// 369.501 us; speedup vs baseline: 1.2443x; 1.1674x over previous
//
#include <hip/hip_runtime.h>
#include <math.h>

#define NLEV 16
#define RES  256
#define NBIN 65536   // 256x256 Morton bins

typedef _Float16 f16;
typedef f16 f16x8 __attribute__((ext_vector_type(8)));
typedef float f32x4 __attribute__((ext_vector_type(4)));

struct LevelMeta {
    float scale[NLEV];
    int   r1[NLEV];    // grid row stride = r+1
    int   off[NLEV];   // element offset into embeddings table
};

struct alignas(8) F4 { float x, y, z, w; };

__device__ inline unsigned spread2d(unsigned v) {
    v = (v | (v << 4)) & 0x0F0Fu;
    v = (v | (v << 2)) & 0x3333u;
    v = (v | (v << 1)) & 0x5555u;
    return v;
}

__device__ inline unsigned bin_of(float x0, float x1) {
    int bx = (int)(x0 * (float)RES); bx = bx < 0 ? 0 : (bx > RES - 1 ? RES - 1 : bx);
    int by = (int)(x1 * (float)RES); by = by < 0 ? 0 : (by > RES - 1 ? RES - 1 : by);
    return spread2d((unsigned)bx) | (spread2d((unsigned)by) << 1);  // [0, NBIN)
}

// ---- zero the histogram ----
__global__ __launch_bounds__(256)
void zero_kernel(unsigned* __restrict__ hist) {
    ((uint4*)hist)[blockIdx.x * 256 + threadIdx.x] = uint4{0, 0, 0, 0};
}

// ---- hist + bin tag + within-bin rank (single atomic pass) ----
__global__ __launch_bounds__(256)
void hist_kernel(const float* __restrict__ x, const float* __restrict__ cmax,
                 unsigned* __restrict__ hist, unsigned short* __restrict__ bin16,
                 unsigned* __restrict__ seq) {
    int p = blockIdx.x * 256 + threadIdx.x;
    float2 xy = ((const float2*)x)[p];
    unsigned b = bin_of(xy.x / cmax[1], xy.y / cmax[0]);
    unsigned s = atomicAdd(&hist[b], 1u);
    bin16[p] = (unsigned short)b;
    seq[p] = s;
}

// ---- scan phase A: per-block (256-bin chunk) sums ----
__global__ __launch_bounds__(256)
void scanA_kernel(const unsigned* __restrict__ hist, unsigned* __restrict__ sums) {
    __shared__ unsigned ws[4];
    int t = threadIdx.x;
    unsigned s = hist[blockIdx.x * 256 + t];
#pragma unroll
    for (int o = 1; o < 64; o <<= 1) s += (unsigned)__shfl_xor((int)s, o);
    if ((t & 63) == 0) ws[t >> 6] = s;
    __syncthreads();
    if (t == 0) sums[blockIdx.x] = ws[0] + ws[1] + ws[2] + ws[3];
}

// ---- scan phase BC: chunk base (reduce sums < blockIdx) + in-chunk exclusive scan ----
__global__ __launch_bounds__(256)
void scanBC_kernel(const unsigned* __restrict__ hist, const unsigned* __restrict__ sums,
                   unsigned* __restrict__ base) {
    __shared__ unsigned ws[4];
    __shared__ unsigned chunk_base;
    int t = threadIdx.x, lane = t & 63, w = t >> 6;

    // chunk base: sum of sums[0..blockIdx) — each thread covers one entry
    {
        unsigned v = (t < blockIdx.x) ? sums[t] : 0u;
#pragma unroll
        for (int o = 1; o < 64; o <<= 1) v += (unsigned)__shfl_xor((int)v, o);
        if (lane == 0) ws[w] = v;
        __syncthreads();
        if (t == 0) chunk_base = ws[0] + ws[1] + ws[2] + ws[3];
        __syncthreads();
    }

    int gb = blockIdx.x * 256 + t;
    unsigned v = hist[gb];
    unsigned xs = v;
#pragma unroll
    for (int o = 1; o < 64; o <<= 1) {
        unsigned y = (unsigned)__shfl_up((int)xs, o);
        if (lane >= o) xs += y;
    }
    __syncthreads();   // ws reuse
    if (lane == 63) ws[w] = xs;
    __syncthreads();
    unsigned wo = 0;
    for (int k = 0; k < w; ++k) wo += ws[k];
    base[gb] = chunk_base + wo + xs - v;
}

// ---- scatter: atomic-free; writes pidx AND sorted normalized coords ----
__global__ __launch_bounds__(256)
void scatter_kernel(const float* __restrict__ x, const float* __restrict__ cmax,
                    const unsigned short* __restrict__ bin16,
                    const unsigned* __restrict__ seq,
                    const unsigned* __restrict__ base,
                    unsigned* __restrict__ pidx, float2* __restrict__ px) {
    int p = blockIdx.x * 256 + threadIdx.x;
    unsigned b = bin16[p];
    unsigned rank = base[b] + seq[p];
    pidx[rank] = (unsigned)p;
    float2 xy = ((const float2*)x)[p];
    float2 v; v.x = xy.x / cmax[1]; v.y = xy.y / cmax[0];
    px[rank] = v;
}

// ---- fused hashgrid + MLP (round-4 structure: LDS weights, 3 WG/CU) ----
// LDS: w0s 5120B + w1s 9216B + w2s 2304B + wbuf 36864B = 53504B -> 3 WG/CU
__global__ __launch_bounds__(256, 3)
void hashmlp_kernel(const float* __restrict__ x,
                    const float* __restrict__ cmax,
                    const unsigned* __restrict__ pidx,   // may be null (fallback)
                    const float2* __restrict__ px,       // may be null
                    const float* __restrict__ emb,
                    const float* __restrict__ w0,
                    const float* __restrict__ b0,
                    const float* __restrict__ w1,
                    const float* __restrict__ b1,
                    const float* __restrict__ w2,
                    const float* __restrict__ b2,
                    float* __restrict__ out,
                    int npts, int nblk,
                    LevelMeta meta)
{
    __shared__ f16 w0s[64 * 40];
    __shared__ f16 w1s[64 * 72];
    __shared__ f16 w2s[16 * 72];
    __shared__ f16 wbuf[4][4608];

    const int tid  = threadIdx.x;
    const int lane = tid & 63;
    const int wave = tid >> 6;

    for (int i = tid; i < 64 * 32; i += 256)
        w0s[(i >> 5) * 40 + (i & 31)] = (f16)w0[i];
    for (int i = tid; i < 64 * 64; i += 256)
        w1s[(i >> 6) * 72 + (i & 63)] = (f16)w1[i];
    for (int i = tid; i < 16 * 64; i += 256) {
        int r = i >> 6, c = i & 63;
        w2s[r * 72 + c] = (r < 3) ? (f16)w2[r * 64 + c] : (f16)0.f;
    }
    __syncthreads();

    // XCD-chunked swizzle: contiguous sorted (spatial) range per XCD
    int bid = blockIdx.x;
    int cpx = nblk >> 3;
    int swz = (bid & 7) * cpx + (bid >> 3);
    const int g = swz * 256 + tid;
    const int gblk = swz * 256 + wave * 64;

    int p;
    float x0, x1;
    if (pidx) {
        p = (int)pidx[g];
        float2 xy = px[g];          // streaming read of sorted coords
        x0 = xy.x; x1 = xy.y;
    } else {
        p = g;
        float2 xy = ((const float2*)x)[p];
        x0 = xy.x / cmax[1];
        x1 = xy.y / cmax[0];
    }

    float fr[32];
#pragma unroll
    for (int l = 0; l < NLEV; ++l) {
        const float sc = meta.scale[l];
        const int r1 = meta.r1[l];
        const int off = meta.off[l];
        float p0 = x0 * sc + 0.5f;
        float p1 = x1 * sc + 0.5f;
        float g0 = floorf(p0), g1 = floorf(p1);
        float f0 = p0 - g0, f1 = p1 - g1;
        int i0 = (int)g0, i1 = (int)g1;
        const float* ebf = emb + 2 * (off + i1 * r1 + i0);
        F4 lo = *(const F4*)ebf;              // e00.x e00.y e10.x e10.y
        F4 hi = *(const F4*)(ebf + 2 * r1);   // e01.x e01.y e11.x e11.y
        float omf0 = 1.f - f0, omf1 = 1.f - f1;
        float w00 = omf0 * omf1, w01 = omf0 * f1, w10 = f0 * omf1, w11 = f0 * f1;
        float a0 = w00 * lo.x; a0 += w01 * hi.x; a0 += w10 * lo.z; a0 += w11 * hi.z;
        float a1 = w00 * lo.y; a1 += w01 * hi.y; a1 += w10 * lo.w; a1 += w11 * hi.w;
        fr[2 * l]     = a0;
        fr[2 * l + 1] = a1;
    }

    // out_lc0 (fp32, exact) at original position
    float* outlc = out + (size_t)npts * 3 + (size_t)p * 32;
#pragma unroll
    for (int c = 0; c < 8; ++c) {
        float4 v;
        v.x = fr[4 * c]; v.y = fr[4 * c + 1]; v.z = fr[4 * c + 2]; v.w = fr[4 * c + 3];
        ((float4*)outlc)[c] = v;
    }

    // stage relu(feats)*2^14 as f16 into per-wave LDS [64][40]
    f16* fbuf = wbuf[wave];
#pragma unroll
    for (int c = 0; c < 4; ++c) {
        f16x8 v;
#pragma unroll
        for (int j = 0; j < 8; ++j)
            v[j] = (f16)(fmaxf(fr[8 * c + j], 0.f) * 16384.f);
        *(f16x8*)&fbuf[lane * 40 + c * 8] = v;
    }

    const int lr = lane & 15;
    const int lg = lane >> 4;
    f16* hbuf = wbuf[wave];

    // layer 0
    {
        f16x8 bf[4];
        float bia[4];
#pragma unroll
        for (int nt = 0; nt < 4; ++nt) {
            bf[nt] = *(const f16x8*)&w0s[(nt * 16 + lr) * 40 + lg * 8];
            bia[nt] = b0[nt * 16 + lr];
        }
#pragma unroll
        for (int mt = 3; mt >= 0; --mt) {
            f16x8 a = *(const f16x8*)&fbuf[(mt * 16 + lr) * 40 + lg * 8];
#pragma unroll
            for (int nt = 0; nt < 4; ++nt) {
                f32x4 c = {0.f, 0.f, 0.f, 0.f};
                c = __builtin_amdgcn_mfma_f32_16x16x32_f16(a, bf[nt], c, 0, 0, 0);
#pragma unroll
                for (int q = 0; q < 4; ++q) {
                    float h = fmaxf(c[q] * (1.0f / 16384.f) + bia[nt], 0.f);
                    hbuf[(mt * 16 + lg * 4 + q) * 72 + nt * 16 + lr] = (f16)h;
                }
            }
        }
    }

    // layer 1
    {
        f16x8 bf[4][2];
        float bia[4];
#pragma unroll
        for (int nt = 0; nt < 4; ++nt) {
            bf[nt][0] = *(const f16x8*)&w1s[(nt * 16 + lr) * 72 + lg * 8];
            bf[nt][1] = *(const f16x8*)&w1s[(nt * 16 + lr) * 72 + 32 + lg * 8];
            bia[nt] = b1[nt * 16 + lr];
        }
#pragma unroll
        for (int mt = 0; mt < 4; ++mt) {
            f16x8 a0 = *(const f16x8*)&hbuf[(mt * 16 + lr) * 72 + lg * 8];
            f16x8 a1 = *(const f16x8*)&hbuf[(mt * 16 + lr) * 72 + 32 + lg * 8];
#pragma unroll
            for (int nt = 0; nt < 4; ++nt) {
                f32x4 c = {0.f, 0.f, 0.f, 0.f};
                c = __builtin_amdgcn_mfma_f32_16x16x32_f16(a0, bf[nt][0], c, 0, 0, 0);
                c = __builtin_amdgcn_mfma_f32_16x16x32_f16(a1, bf[nt][1], c, 0, 0, 0);
#pragma unroll
                for (int q = 0; q < 4; ++q) {
                    float h = fmaxf(c[q] + bia[nt], 0.f);
                    hbuf[(mt * 16 + lg * 4 + q) * 72 + nt * 16 + lr] = (f16)h;
                }
            }
        }
    }

    // layer 2 -> h output at original positions
    {
        f16x8 bf0 = *(const f16x8*)&w2s[lr * 72 + lg * 8];
        f16x8 bf1 = *(const f16x8*)&w2s[lr * 72 + 32 + lg * 8];
        float bia2 = (lr < 3) ? b2[lr] : 0.f;
#pragma unroll
        for (int mt = 0; mt < 4; ++mt) {
            f16x8 a0 = *(const f16x8*)&hbuf[(mt * 16 + lr) * 72 + lg * 8];
            f16x8 a1 = *(const f16x8*)&hbuf[(mt * 16 + lr) * 72 + 32 + lg * 8];
            f32x4 c = {0.f, 0.f, 0.f, 0.f};
            c = __builtin_amdgcn_mfma_f32_16x16x32_f16(a0, bf0, c, 0, 0, 0);
            c = __builtin_amdgcn_mfma_f32_16x16x32_f16(a1, bf1, c, 0, 0, 0);
            if (lr < 3) {
#pragma unroll
                for (int q = 0; q < 4; ++q) {
                    int row = mt * 16 + lg * 4 + q;
                    int po = pidx ? (int)pidx[gblk + row] : (gblk + row);
                    out[(size_t)po * 3 + lr] = c[q] + bia2;
                }
            }
        }
    }
}

extern "C" void kernel_launch(void* const* d_in, const int* in_sizes, int n_in,
                              void* d_out, int out_size, void* d_ws, size_t ws_size,
                              hipStream_t stream) {
    const float* x    = (const float*)d_in[0];
    const float* cmax = (const float*)d_in[1];
    const float* emb  = (const float*)d_in[2];
    const float* w0   = (const float*)d_in[3];
    const float* b0   = (const float*)d_in[4];
    const float* w1   = (const float*)d_in[5];
    const float* b1   = (const float*)d_in[6];
    const float* w2   = (const float*)d_in[7];
    const float* b2   = (const float*)d_in[8];
    const int npts = in_sizes[0] / 2;
    const int nblk = npts / 256;

    LevelMeta meta;
    const double S = log2(2048.0 / 16.0) / 15.0;
    long long off = 0;
    for (int l = 0; l < NLEV; ++l) {
        double s = pow(2.0, l * S) * 16.0 - 1.0;
        int r = (int)ceil(s) + 1;
        long long pc = (long long)(r + 1) * (r + 1);
        if (pc > (1ll << 24)) pc = (1ll << 24);
        pc = ((pc + 7) / 8) * 8;
        meta.scale[l] = (float)s;
        meta.r1[l]    = r + 1;
        meta.off[l]   = (int)off;
        off += pc;
    }

    // ws: hist[NBIN] u32 | base[NBIN] u32 | sums[256] u32 | pidx u32 | seq u32 | px f2 | bin16 u16
    size_t need = (size_t)NBIN * 8 + 256 * 4 + (size_t)npts * 18;
    if (ws_size >= need && (npts & 255) == 0 && (nblk & 7) == 0) {
        unsigned* hist = (unsigned*)d_ws;
        unsigned* base = hist + NBIN;
        unsigned* sums = base + NBIN;
        unsigned* pidx = sums + 256;
        unsigned* seq  = pidx + npts;
        float2*   px   = (float2*)(seq + npts);
        unsigned short* bin16 = (unsigned short*)(px + npts);

        hipLaunchKernelGGL(zero_kernel, dim3(NBIN / 1024), dim3(256), 0, stream, hist);
        hipLaunchKernelGGL(hist_kernel, dim3(nblk), dim3(256), 0, stream, x, cmax, hist, bin16, seq);
        hipLaunchKernelGGL(scanA_kernel, dim3(NBIN / 256), dim3(256), 0, stream, hist, sums);
        hipLaunchKernelGGL(scanBC_kernel, dim3(NBIN / 256), dim3(256), 0, stream, hist, sums, base);
        hipLaunchKernelGGL(scatter_kernel, dim3(nblk), dim3(256), 0, stream, x, cmax, bin16, seq, base, pidx, px);
        hipLaunchKernelGGL(hashmlp_kernel, dim3(nblk), dim3(256), 0, stream,
                           x, cmax, pidx, px, emb, w0, b0, w1, b1, w2, b2,
                           (float*)d_out, npts, nblk, meta);
    } else {
        hipLaunchKernelGGL(hashmlp_kernel, dim3(nblk), dim3(256), 0, stream,
                           x, cmax, (const unsigned*)nullptr, (const float2*)nullptr,
                           emb, w0, b0, w1, b1, w2, b2,
                           (float*)d_out, npts, nblk, meta);
    }
}

// Round 12
// 366.472 us; speedup vs baseline: 1.2545x; 1.0083x over previous
//
#include <hip/hip_runtime.h>
#include <math.h>

#define NLEV 16
#define RES  256
#define NBIN 65536   // 256x256 Morton bins

typedef _Float16 f16;
typedef f16 f16x8 __attribute__((ext_vector_type(8)));
typedef float f32x4 __attribute__((ext_vector_type(4)));

struct LevelMeta {
    float scale[NLEV];
    int   r1[NLEV];    // grid row stride = r+1
    int   off[NLEV];   // element offset into embeddings table
};

struct alignas(8) F4 { float x, y, z, w; };

__device__ inline unsigned spread2d(unsigned v) {
    v = (v | (v << 4)) & 0x0F0Fu;
    v = (v | (v << 2)) & 0x3333u;
    v = (v | (v << 1)) & 0x5555u;
    return v;
}

__device__ inline unsigned bin_of(float x0, float x1) {
    int bx = (int)(x0 * (float)RES); bx = bx < 0 ? 0 : (bx > RES - 1 ? RES - 1 : bx);
    int by = (int)(x1 * (float)RES); by = by < 0 ? 0 : (by > RES - 1 ? RES - 1 : by);
    return spread2d((unsigned)bx) | (spread2d((unsigned)by) << 1);  // [0, NBIN)
}

// ---- zero the histogram ----
__global__ __launch_bounds__(256)
void zero_kernel(unsigned* __restrict__ hist) {
    ((uint4*)hist)[blockIdx.x * 256 + threadIdx.x] = uint4{0, 0, 0, 0};
}

// ---- hist + packed (bin<<16 | within-bin-rank) ----
__global__ __launch_bounds__(256)
void hist_kernel(const float* __restrict__ x, const float* __restrict__ cmax,
                 unsigned* __restrict__ hist, unsigned* __restrict__ rec) {
    int p = blockIdx.x * 256 + threadIdx.x;
    float2 xy = ((const float2*)x)[p];
    unsigned b = bin_of(xy.x / cmax[1], xy.y / cmax[0]);
    unsigned s = atomicAdd(&hist[b], 1u);
    rec[p] = (b << 16) | (s & 0xFFFFu);
}

// ---- scan phase A: per-block (256-bin chunk) sums ----
__global__ __launch_bounds__(256)
void scanA_kernel(const unsigned* __restrict__ hist, unsigned* __restrict__ sums) {
    __shared__ unsigned ws[4];
    int t = threadIdx.x;
    unsigned s = hist[blockIdx.x * 256 + t];
#pragma unroll
    for (int o = 1; o < 64; o <<= 1) s += (unsigned)__shfl_xor((int)s, o);
    if ((t & 63) == 0) ws[t >> 6] = s;
    __syncthreads();
    if (t == 0) sums[blockIdx.x] = ws[0] + ws[1] + ws[2] + ws[3];
}

// ---- scan phase BC: chunk base (reduce sums < blockIdx) + in-chunk exclusive scan ----
__global__ __launch_bounds__(256)
void scanBC_kernel(const unsigned* __restrict__ hist, const unsigned* __restrict__ sums,
                   unsigned* __restrict__ base) {
    __shared__ unsigned ws[4];
    __shared__ unsigned chunk_base;
    int t = threadIdx.x, lane = t & 63, w = t >> 6;

    {
        unsigned v = (t < blockIdx.x) ? sums[t] : 0u;
#pragma unroll
        for (int o = 1; o < 64; o <<= 1) v += (unsigned)__shfl_xor((int)v, o);
        if (lane == 0) ws[w] = v;
        __syncthreads();
        if (t == 0) chunk_base = ws[0] + ws[1] + ws[2] + ws[3];
        __syncthreads();
    }

    int gb = blockIdx.x * 256 + t;
    unsigned v = hist[gb];
    unsigned xs = v;
#pragma unroll
    for (int o = 1; o < 64; o <<= 1) {
        unsigned y = (unsigned)__shfl_up((int)xs, o);
        if (lane >= o) xs += y;
    }
    __syncthreads();
    if (lane == 63) ws[w] = xs;
    __syncthreads();
    unsigned wo = 0;
    for (int k = 0; k < w; ++k) wo += ws[k];
    base[gb] = chunk_base + wo + xs - v;
}

// ---- scatter: atomic-free; writes pidx AND sorted normalized coords ----
__global__ __launch_bounds__(256)
void scatter_kernel(const float* __restrict__ x, const float* __restrict__ cmax,
                    const unsigned* __restrict__ rec,
                    const unsigned* __restrict__ base,
                    unsigned* __restrict__ pidx, float2* __restrict__ px) {
    int p = blockIdx.x * 256 + threadIdx.x;
    unsigned r = rec[p];
    unsigned rank = base[r >> 16] + (r & 0xFFFFu);
    pidx[rank] = (unsigned)p;
    float2 xy = ((const float2*)x)[p];
    float2 v; v.x = xy.x / cmax[1]; v.y = xy.y / cmax[0];
    px[rank] = v;
}

// ---- fused hashgrid + MLP (LDS weights, 3 WG/CU; staging split issue-early/store-late) ----
// LDS: w0s 5120B + w1s 9216B + w2s 2304B + wbuf 36864B = 53504B -> 3 WG/CU
__global__ __launch_bounds__(256, 3)
void hashmlp_kernel(const float* __restrict__ x,
                    const float* __restrict__ cmax,
                    const unsigned* __restrict__ pidx,   // may be null (fallback)
                    const float2* __restrict__ px,       // may be null
                    const float* __restrict__ emb,
                    const float* __restrict__ w0,
                    const float* __restrict__ b0,
                    const float* __restrict__ w1,
                    const float* __restrict__ b1,
                    const float* __restrict__ w2,
                    const float* __restrict__ b2,
                    float* __restrict__ out,
                    int npts, int nblk,
                    LevelMeta meta)
{
    __shared__ f16 w0s[64 * 40];
    __shared__ f16 w1s[64 * 72];
    __shared__ f16 w2s[16 * 72];
    __shared__ f16 wbuf[4][4608];

    const int tid  = threadIdx.x;
    const int lane = tid & 63;
    const int wave = tid >> 6;

    // ---- phase 1: weight LOADS into registers (issue before gathers; stores deferred) ----
    float w0t[8], w1t[16], w2t[4];
#pragma unroll
    for (int k = 0; k < 8; ++k)  w0t[k] = w0[tid + 256 * k];
#pragma unroll
    for (int k = 0; k < 16; ++k) w1t[k] = w1[tid + 256 * k];
#pragma unroll
    for (int k = 0; k < 4; ++k) {
        int i = tid + 256 * k; int r = i >> 6, c = i & 63;
        w2t[k] = (r < 3) ? w2[r * 64 + c] : 0.f;
    }

    // XCD-chunked swizzle: contiguous sorted (spatial) range per XCD
    int bid = blockIdx.x;
    int cpx = nblk >> 3;
    int swz = (bid & 7) * cpx + (bid >> 3);
    const int g = swz * 256 + tid;
    const int gblk = swz * 256 + wave * 64;

    int p;
    float x0, x1;
    if (pidx) {
        p = (int)pidx[g];
        float2 xy = px[g];          // streaming read of sorted coords
        x0 = xy.x; x1 = xy.y;
    } else {
        p = g;
        float2 xy = ((const float2*)x)[p];
        x0 = xy.x / cmax[1];
        x1 = xy.y / cmax[0];
    }

    // ---- phase 2: gather (compiler-scheduled; weight loads overlap the stalls) ----
    float fr[32];
#pragma unroll
    for (int l = 0; l < NLEV; ++l) {
        const float sc = meta.scale[l];
        const int r1 = meta.r1[l];
        const int off = meta.off[l];
        float p0 = x0 * sc + 0.5f;
        float p1 = x1 * sc + 0.5f;
        float g0 = floorf(p0), g1 = floorf(p1);
        float f0 = p0 - g0, f1 = p1 - g1;
        int i0 = (int)g0, i1 = (int)g1;
        const float* ebf = emb + 2 * (off + i1 * r1 + i0);
        F4 lo = *(const F4*)ebf;              // e00.x e00.y e10.x e10.y
        F4 hi = *(const F4*)(ebf + 2 * r1);   // e01.x e01.y e11.x e11.y
        float omf0 = 1.f - f0, omf1 = 1.f - f1;
        float w00 = omf0 * omf1, w01 = omf0 * f1, w10 = f0 * omf1, w11 = f0 * f1;
        float a0 = w00 * lo.x; a0 += w01 * hi.x; a0 += w10 * lo.z; a0 += w11 * hi.z;
        float a1 = w00 * lo.y; a1 += w01 * hi.y; a1 += w10 * lo.w; a1 += w11 * hi.w;
        fr[2 * l]     = a0;
        fr[2 * l + 1] = a1;
    }

    // ---- phase 3: weight STORES to LDS ----
#pragma unroll
    for (int k = 0; k < 8; ++k)  { int i = tid + 256 * k; w0s[(i >> 5) * 40 + (i & 31)] = (f16)w0t[k]; }
#pragma unroll
    for (int k = 0; k < 16; ++k) { int i = tid + 256 * k; w1s[(i >> 6) * 72 + (i & 63)] = (f16)w1t[k]; }
#pragma unroll
    for (int k = 0; k < 4; ++k)  { int i = tid + 256 * k; w2s[(i >> 6) * 72 + (i & 63)] = (f16)w2t[k]; }

    // out_lc0 (fp32, exact) at original position
    float* outlc = out + (size_t)npts * 3 + (size_t)p * 32;
#pragma unroll
    for (int c = 0; c < 8; ++c) {
        float4 v;
        v.x = fr[4 * c]; v.y = fr[4 * c + 1]; v.z = fr[4 * c + 2]; v.w = fr[4 * c + 3];
        ((float4*)outlc)[c] = v;
    }

    // stage relu(feats)*2^14 as f16 into per-wave LDS [64][40] (own-wave buffer, pre-sync OK)
    f16* fbuf = wbuf[wave];
#pragma unroll
    for (int c = 0; c < 4; ++c) {
        f16x8 v;
#pragma unroll
        for (int j = 0; j < 8; ++j)
            v[j] = (f16)(fmaxf(fr[8 * c + j], 0.f) * 16384.f);
        *(f16x8*)&fbuf[lane * 40 + c * 8] = v;
    }

    __syncthreads();   // weights visible to all waves

    const int lr = lane & 15;
    const int lg = lane >> 4;
    f16* hbuf = wbuf[wave];

    // layer 0
    {
        f16x8 bf[4];
        float bia[4];
#pragma unroll
        for (int nt = 0; nt < 4; ++nt) {
            bf[nt] = *(const f16x8*)&w0s[(nt * 16 + lr) * 40 + lg * 8];
            bia[nt] = b0[nt * 16 + lr];
        }
#pragma unroll
        for (int mt = 3; mt >= 0; --mt) {
            f16x8 a = *(const f16x8*)&fbuf[(mt * 16 + lr) * 40 + lg * 8];
#pragma unroll
            for (int nt = 0; nt < 4; ++nt) {
                f32x4 c = {0.f, 0.f, 0.f, 0.f};
                c = __builtin_amdgcn_mfma_f32_16x16x32_f16(a, bf[nt], c, 0, 0, 0);
#pragma unroll
                for (int q = 0; q < 4; ++q) {
                    float h = fmaxf(c[q] * (1.0f / 16384.f) + bia[nt], 0.f);
                    hbuf[(mt * 16 + lg * 4 + q) * 72 + nt * 16 + lr] = (f16)h;
                }
            }
        }
    }

    // layer 1
    {
        f16x8 bf[4][2];
        float bia[4];
#pragma unroll
        for (int nt = 0; nt < 4; ++nt) {
            bf[nt][0] = *(const f16x8*)&w1s[(nt * 16 + lr) * 72 + lg * 8];
            bf[nt][1] = *(const f16x8*)&w1s[(nt * 16 + lr) * 72 + 32 + lg * 8];
            bia[nt] = b1[nt * 16 + lr];
        }
#pragma unroll
        for (int mt = 0; mt < 4; ++mt) {
            f16x8 a0 = *(const f16x8*)&hbuf[(mt * 16 + lr) * 72 + lg * 8];
            f16x8 a1 = *(const f16x8*)&hbuf[(mt * 16 + lr) * 72 + 32 + lg * 8];
#pragma unroll
            for (int nt = 0; nt < 4; ++nt) {
                f32x4 c = {0.f, 0.f, 0.f, 0.f};
                c = __builtin_amdgcn_mfma_f32_16x16x32_f16(a0, bf[nt][0], c, 0, 0, 0);
                c = __builtin_amdgcn_mfma_f32_16x16x32_f16(a1, bf[nt][1], c, 0, 0, 0);
#pragma unroll
                for (int q = 0; q < 4; ++q) {
                    float h = fmaxf(c[q] + bia[nt], 0.f);
                    hbuf[(mt * 16 + lg * 4 + q) * 72 + nt * 16 + lr] = (f16)h;
                }
            }
        }
    }

    // layer 2 -> h output at original positions
    {
        f16x8 bf0 = *(const f16x8*)&w2s[lr * 72 + lg * 8];
        f16x8 bf1 = *(const f16x8*)&w2s[lr * 72 + 32 + lg * 8];
        float bia2 = (lr < 3) ? b2[lr] : 0.f;
#pragma unroll
        for (int mt = 0; mt < 4; ++mt) {
            f16x8 a0 = *(const f16x8*)&hbuf[(mt * 16 + lr) * 72 + lg * 8];
            f16x8 a1 = *(const f16x8*)&hbuf[(mt * 16 + lr) * 72 + 32 + lg * 8];
            f32x4 c = {0.f, 0.f, 0.f, 0.f};
            c = __builtin_amdgcn_mfma_f32_16x16x32_f16(a0, bf0, c, 0, 0, 0);
            c = __builtin_amdgcn_mfma_f32_16x16x32_f16(a1, bf1, c, 0, 0, 0);
            if (lr < 3) {
#pragma unroll
                for (int q = 0; q < 4; ++q) {
                    int row = mt * 16 + lg * 4 + q;
                    int po = pidx ? (int)pidx[gblk + row] : (gblk + row);
                    out[(size_t)po * 3 + lr] = c[q] + bia2;
                }
            }
        }
    }
}

extern "C" void kernel_launch(void* const* d_in, const int* in_sizes, int n_in,
                              void* d_out, int out_size, void* d_ws, size_t ws_size,
                              hipStream_t stream) {
    const float* x    = (const float*)d_in[0];
    const float* cmax = (const float*)d_in[1];
    const float* emb  = (const float*)d_in[2];
    const float* w0   = (const float*)d_in[3];
    const float* b0   = (const float*)d_in[4];
    const float* w1   = (const float*)d_in[5];
    const float* b1   = (const float*)d_in[6];
    const float* w2   = (const float*)d_in[7];
    const float* b2   = (const float*)d_in[8];
    const int npts = in_sizes[0] / 2;
    const int nblk = npts / 256;

    LevelMeta meta;
    const double S = log2(2048.0 / 16.0) / 15.0;
    long long off = 0;
    for (int l = 0; l < NLEV; ++l) {
        double s = pow(2.0, l * S) * 16.0 - 1.0;
        int r = (int)ceil(s) + 1;
        long long pc = (long long)(r + 1) * (r + 1);
        if (pc > (1ll << 24)) pc = (1ll << 24);
        pc = ((pc + 7) / 8) * 8;
        meta.scale[l] = (float)s;
        meta.r1[l]    = r + 1;
        meta.off[l]   = (int)off;
        off += pc;
    }

    // ws: hist[NBIN] u32 | base[NBIN] u32 | sums[256] u32 | pidx u32 | rec u32 | px f2
    size_t need = (size_t)NBIN * 8 + 256 * 4 + (size_t)npts * 16;
    if (ws_size >= need && (npts & 255) == 0 && (nblk & 7) == 0) {
        unsigned* hist = (unsigned*)d_ws;
        unsigned* base = hist + NBIN;
        unsigned* sums = base + NBIN;
        unsigned* pidx = sums + 256;
        unsigned* rec  = pidx + npts;
        float2*   px   = (float2*)(rec + npts);

        hipLaunchKernelGGL(zero_kernel, dim3(NBIN / 1024), dim3(256), 0, stream, hist);
        hipLaunchKernelGGL(hist_kernel, dim3(nblk), dim3(256), 0, stream, x, cmax, hist, rec);
        hipLaunchKernelGGL(scanA_kernel, dim3(NBIN / 256), dim3(256), 0, stream, hist, sums);
        hipLaunchKernelGGL(scanBC_kernel, dim3(NBIN / 256), dim3(256), 0, stream, hist, sums, base);
        hipLaunchKernelGGL(scatter_kernel, dim3(nblk), dim3(256), 0, stream, x, cmax, rec, base, pidx, px);
        hipLaunchKernelGGL(hashmlp_kernel, dim3(nblk), dim3(256), 0, stream,
                           x, cmax, pidx, px, emb, w0, b0, w1, b1, w2, b2,
                           (float*)d_out, npts, nblk, meta);
    } else {
        hipLaunchKernelGGL(hashmlp_kernel, dim3(nblk), dim3(256), 0, stream,
                           x, cmax, (const unsigned*)nullptr, (const float2*)nullptr,
                           emb, w0, b0, w1, b1, w2, b2,
                           (float*)d_out, npts, nblk, meta);
    }
}